// Round 9
// baseline (281.525 us; speedup 1.0000x reference)
//
#include <hip/hip_runtime.h>
#include <hip/hip_bf16.h>
#include <stdint.h>

// Problem constants (fixed by reference)
#define B_  4
#define N_  8192
#define M_  8192
#define D_  64
#define KP  96    // padded K: 64 data + (norm_hi, norm_lo, 1, 1) + 28 zeros
#define NT_ 64
#define MT_ 64
#define RBN ((B_ * N_) / 16)     // 2048 16-row blocks on A side
#define INF_BITS 0x7F800000      // +inf bits; signed-int min == float min for our range
#define GRID_TILE (8 * 64 * 4)   // tile grid size (mc,nt,b)

typedef __attribute__((ext_vector_type(8))) short bhalf8;   // 8 bf16 (MFMA A/B frag)
typedef __attribute__((ext_vector_type(4))) float f32x4;    // MFMA C/D frag

// ---- workspace layout (bytes) ----
// A'/B': bf16 fragment-chunk order: chunk(rb, ks, lane=q*16+c) = row (rb*16+c), k=ks*32+q*8..+7,
//        at ((rb*3+ks)*64+lane)*8 elems -> lane-contiguous 1KB fragment loads.
// K extension fuses norms: A' row = (-2f, nh, nl, 1, 1, 0...), B' row = (f_, 1, 1, nh2, nl2, 0...)
//   => A'.B' = full squared distance straight out of MFMA.
// rowglob/colglob: per-point mins as float bits (int), atomicMin-accumulated; counter after them.
static const size_t OFF_A   = 0;
static const size_t OFF_B   = (size_t)B_ * N_ * KP * 2;                   // 6,291,456
static const size_t OFF_RG  = OFF_B + (size_t)B_ * M_ * KP * 2;           // 12,582,912
static const size_t OFF_CG  = OFF_RG + (size_t)B_ * N_ * 4;               // +128 KB
static const size_t OFF_CNT = OFF_CG + (size_t)B_ * M_ * 4;               // +128 KB

__device__ __forceinline__ short bf16bits(float x) {
    union { __hip_bfloat16 h; unsigned short u; } cv;
    cv.h = __float2bfloat16(x);
    return (short)cv.u;
}
__device__ __forceinline__ float min3f(float a, float b, float c) {
    return fminf(fminf(a, b), c);   // -> v_min3_f32
}

// ---------------- prep: K=96 fused-norm fragment layout; init min buffers + counter + out ----------------
__global__ __launch_bounds__(256) void chamfer_prep(
        const float* __restrict__ f, const float* __restrict__ f2,
        unsigned short* __restrict__ Ap, unsigned short* __restrict__ Bp,
        int* __restrict__ minbuf, float* __restrict__ out) {
    const int tid = threadIdx.x;
    const int gid = blockIdx.x * 256 + tid;
    if (gid == 0) out[0] = 0.f;
    if (gid <= 65536) minbuf[gid] = (gid == 65536) ? 0 : INF_BITS;  // rowglob+colglob+counter

    const int w = gid >> 6;                          // 16-row block id, 0..4095
    const int lane = tid & 63;
    const int q = lane >> 4, c = lane & 15;
    const bool isA = w < RBN;
    const int rb = isA ? w : w - RBN;
    const float* src = isA ? f : f2;
    unsigned short* dst = isA ? Ap : Bp;
    const float scale = isA ? -2.0f : 1.0f;          // fold the -2 into A; exact in bf16

    const float* row = src + ((size_t)rb * 16 + c) * 64;
    f32x4 u0 = *(const f32x4*)(row + q * 8);
    f32x4 u1 = *(const f32x4*)(row + q * 8 + 4);
    f32x4 u2 = *(const f32x4*)(row + 32 + q * 8);
    f32x4 u3 = *(const f32x4*)(row + 32 + q * 8 + 4);

    float ss = 0.f;
    #pragma unroll
    for (int k = 0; k < 4; k++)
        ss += u0[k] * u0[k] + u1[k] * u1[k] + u2[k] * u2[k] + u3[k] * u3[k];
    ss += __shfl_xor(ss, 16, 64);
    ss += __shfl_xor(ss, 32, 64);                    // full ||row c||^2 in every lane

    bhalf8 o0, o1;
    #pragma unroll
    for (int k = 0; k < 4; k++) {
        o0[k]     = bf16bits(u0[k] * scale);
        o0[4 + k] = bf16bits(u1[k] * scale);
        o1[k]     = bf16bits(u2[k] * scale);
        o1[4 + k] = bf16bits(u3[k] * scale);
    }
    bhalf8 o2 = {0, 0, 0, 0, 0, 0, 0, 0};            // k=64..95 zeros except q==0 lanes
    if (q == 0) {
        float nh = __bfloat162float(__float2bfloat16(ss));  // hi part, exact in bf16
        float nl = ss - nh;                                  // residual
        const short one = 0x3F80;                            // bf16 1.0
        if (isA) { o2[0] = bf16bits(nh); o2[1] = bf16bits(nl); o2[2] = one; o2[3] = one; }
        else     { o2[0] = one; o2[1] = one; o2[2] = bf16bits(nh); o2[3] = bf16bits(nl); }
    }
    *(bhalf8*)(dst + ((size_t)(rb * 3 + 0) * 64 + lane) * 8) = o0;
    *(bhalf8*)(dst + ((size_t)(rb * 3 + 1) * 64 + lane) * 8) = o1;
    *(bhalf8*)(dst + ((size_t)(rb * 3 + 2) * 64 + lane) * 8) = o2;
}

// ---------------- tile kernel: wait-free loop, plain ds_write col partials, fused finalize ----------------
// grid (mc=8, nt=64, b=4); wave tile 64 rows x 32 cols/step, 16 steps. Row-min in registers;
// col partial per (owner=wr*4+q) via plain ds_write (owner stride 136 words -> 2-way banks, free;
// every slot written exactly once -> no init, no atomics, no conflicts). Block end: LDS owner-reduce
// -> global atomicMin; last block (device counter) computes the scalar in-kernel.
__global__ __launch_bounds__(256, 4) void chamfer_tile(
        const unsigned short* __restrict__ Ap, const unsigned short* __restrict__ Bp,
        int* __restrict__ rowglob, int* __restrict__ colglob,
        int* __restrict__ counter, float* __restrict__ out) {
    const int mc = blockIdx.x;   // 0..7 : 8-tile mt chunk
    const int nt = blockIdx.y;   // 0..63
    const int b  = blockIdx.z;   // 0..3
    const int tid = threadIdx.x;
    const int wave = tid >> 6, lane = tid & 63;
    const int wr = wave >> 1, wc = wave & 1;
    const int q = lane >> 4, c = lane & 15;

    __shared__ float colmin[8 * 8 * 136];   // [mtl][owner wr*4+q][136]; 34,816 B
    __shared__ int rowmin[128];
    if (tid < 128) rowmin[tid] = INF_BITS;
    __syncthreads();

    // A fragments: rows nt*128 + wr*64 + i*16 + c, 3 k-steps. Loaded once.
    const int rbA0 = b * 512 + nt * 8 + wr * 4;
    bhalf8 af[4][3];
    #pragma unroll
    for (int i = 0; i < 4; i++)
        #pragma unroll
        for (int ks = 0; ks < 3; ks++)
            af[i][ks] = *(const bhalf8*)(Ap + ((size_t)((rbA0 + i) * 3 + ks) * 64 + lane) * 8);

    f32x4 rv[4];                 // running row-min, rows i*16+q*4+r (this wave's 64 rows)
    #pragma unroll
    for (int i = 0; i < 4; i++) rv[i] = (f32x4){3.0e38f, 3.0e38f, 3.0e38f, 3.0e38f};

    const f32x4 zero4 = {0.f, 0.f, 0.f, 0.f};

    // LDS write base for this thread's owner slot (mtl/half/jj offsets are immediates)
    float* cbase = &colmin[(size_t)(wr * 4 + q) * 136 + wc * 64 + c];

    // step: rbB = b*512 + (mc*8+mtl)*8 + wc*4 + half*2 + jj; ptr stride 1536 shorts/rb
    const unsigned short* pE = Bp + (size_t)(b * 512 + mc * 64 + wc * 4) * 1536 + lane * 8;
    const unsigned short* pO = pE + 3072;   // half=1 -> +2 rb

    auto loadB = [&](const unsigned short* p, bhalf8 (&bf)[2][3]) {
        #pragma unroll
        for (int jj = 0; jj < 2; jj++)
            #pragma unroll
            for (int ks = 0; ks < 3; ks++)
                bf[jj][ks] = *(const bhalf8*)(p + jj * 1536 + ks * 512);
    };

    auto process = [&](int mtl, int half, bhalf8 (&bf)[2][3]) {
        f32x4 acc[4][2];
        #pragma unroll
        for (int i = 0; i < 4; i++)
            #pragma unroll
            for (int jj = 0; jj < 2; jj++)
                acc[i][jj] = __builtin_amdgcn_mfma_f32_16x16x32_bf16(af[i][0], bf[jj][0], zero4, 0, 0, 0);
        #pragma unroll
        for (int ks = 1; ks < 3; ks++)
            #pragma unroll
            for (int i = 0; i < 4; i++)
                #pragma unroll
                for (int jj = 0; jj < 2; jj++)
                    acc[i][jj] = __builtin_amdgcn_mfma_f32_16x16x32_bf16(af[i][ks], bf[jj][ks], acc[i][jj], 0, 0, 0);

        // row-min: 16 v_min3
        #pragma unroll
        for (int i = 0; i < 4; i++)
            #pragma unroll
            for (int r = 0; r < 4; r++)
                rv[i][r] = fminf(fminf(acc[i][0][r], acc[i][1][r]), rv[i][r]);

        // col partial over this lane's 16 rows: balanced min3 tree -> ONE plain ds_write
        #pragma unroll
        for (int jj = 0; jj < 2; jj++) {
            float t0 = min3f(acc[0][jj][0], acc[0][jj][1], acc[0][jj][2]);
            float t1 = min3f(acc[0][jj][3], acc[1][jj][0], acc[1][jj][1]);
            float t2 = min3f(acc[1][jj][2], acc[1][jj][3], acc[2][jj][0]);
            float t3 = min3f(acc[2][jj][1], acc[2][jj][2], acc[2][jj][3]);
            float t4 = min3f(acc[3][jj][0], acc[3][jj][1], acc[3][jj][2]);
            cbase[mtl * (8 * 136) + half * 32 + jj * 16]
                = fminf(min3f(t0, t1, t2), min3f(t3, t4, acc[3][jj][3]));
        }
    };

    bhalf8 bf0[2][3], bf1[2][3];
    loadB(pE, bf0);
    #pragma unroll 1
    for (int mtl = 0; mtl < 8; mtl++) {
        loadB(pO, bf1);
        process(mtl, 0, bf0);
        pE += 12288;
        if (mtl < 7) loadB(pE, bf0);
        process(mtl, 1, bf1);
        pO += 12288;
    }

    // row flush (once per block): LDS atomic combine across the 32 (wc,c) owners
    #pragma unroll
    for (int i = 0; i < 4; i++)
        #pragma unroll
        for (int r = 0; r < 4; r++)
            atomicMin(&rowmin[wr * 64 + i * 16 + q * 4 + r], __float_as_int(rv[i][r]));
    __syncthreads();   // drains all ds_writes + row atomics

    if (tid < 128)
        atomicMin(&rowglob[(size_t)(b * 64 + nt) * 128 + tid], rowmin[tid]);
    #pragma unroll
    for (int k = 0; k < 4; k++) {
        const int idx = k * 256 + tid;       // 0..1023 = mtl*128 + col
        const int mtl = idx >> 7, col = idx & 127;
        const float* cp = &colmin[(size_t)mtl * (8 * 136) + col];
        float m = min3f(cp[0], cp[136], cp[2 * 136]);
        m = fminf(m, min3f(cp[3 * 136], cp[4 * 136], cp[5 * 136]));
        m = fminf(m, fminf(cp[6 * 136], cp[7 * 136]));
        atomicMin(&colglob[(size_t)(b * 64 + mc * 8 + mtl) * 128 + col], __float_as_int(m));
    }

    // ---- last-block finalize (saves one kernel launch ~16us) ----
    __shared__ int amLast;
    __syncthreads();   // all global atomics of this block issued & drained (barrier waits vmcnt)
    if (tid == 0) {
        __threadfence();                                  // release our atomics
        amLast = (atomicAdd(counter, 1) == GRID_TILE - 1);
    }
    __syncthreads();
    if (amLast) {
        __threadfence();                                  // acquire others' atomics
        float s = 0.f;
        for (int i = tid; i < B_ * N_; i += 256) {
            int rb_ = __hip_atomic_load(&rowglob[i], __ATOMIC_RELAXED, __HIP_MEMORY_SCOPE_AGENT);
            int cb_ = __hip_atomic_load(&colglob[i], __ATOMIC_RELAXED, __HIP_MEMORY_SCOPE_AGENT);
            s += __int_as_float(rb_) + __int_as_float(cb_);
        }
        s *= (1.0f / ((float)B_ * (float)N_));            // N_ == M_
        __shared__ float sb[256];
        sb[tid] = s;
        __syncthreads();
        for (int st = 128; st > 0; st >>= 1) {
            if (tid < st) sb[tid] += sb[tid + st];
            __syncthreads();
        }
        if (tid == 0) out[0] = sb[0];
    }
}

extern "C" void kernel_launch(void* const* d_in, const int* in_sizes, int n_in,
                              void* d_out, int out_size, void* d_ws, size_t ws_size,
                              hipStream_t stream) {
    const float* f  = (const float*)d_in[0];
    const float* f2 = (const float*)d_in[1];
    char* ws = (char*)d_ws;
    unsigned short* Ap = (unsigned short*)(ws + OFF_A);
    unsigned short* Bp = (unsigned short*)(ws + OFF_B);
    int* rowglob = (int*)(ws + OFF_RG);
    int* colglob = (int*)(ws + OFF_CG);
    int* counter = (int*)(ws + OFF_CNT);
    float* out   = (float*)d_out;

    // prep: fragment layout + norm fusion; inits rowglob/colglob/counter/out
    chamfer_prep<<<dim3(1024), dim3(256), 0, stream>>>(f, f2, Ap, Bp, rowglob, out);

    // main: 2048 blocks; last block computes the scalar
    chamfer_tile<<<dim3(8, NT_, B_), dim3(256), 0, stream>>>(Ap, Bp, rowglob, colglob, counter, out);
}

// Round 10
// 183.678 us; speedup vs baseline: 1.5327x; 1.5327x over previous
//
#include <hip/hip_runtime.h>
#include <hip/hip_bf16.h>
#include <stdint.h>

// Problem constants (fixed by reference)
#define B_  4
#define N_  8192
#define M_  8192
#define D_  64
#define KP  96    // padded K: 64 data + (norm_hi, norm_lo, 1, 1) + 28 zeros
#define NT_ 64
#define MT_ 64
#define RBN ((B_ * N_) / 16)     // 2048 16-row blocks on A side
#define INF_BITS 0x7F800000      // +inf bits; signed-int min == float min for our range
#define GRID_TILE (8 * 64 * 4)   // tile grid size (mc,nt,b)

typedef __attribute__((ext_vector_type(8))) short bhalf8;   // 8 bf16 (MFMA A/B frag)
typedef __attribute__((ext_vector_type(4))) float f32x4;    // MFMA C/D frag

// ---- workspace layout (bytes) ----
// A'/B': bf16 fragment-chunk order: chunk(rb, ks, lane=q*16+c) = row (rb*16+c), k=ks*32+q*8..+7,
//        at ((rb*3+ks)*64+lane)*8 elems -> lane-contiguous 1KB fragment loads.
// K extension fuses norms: A' row = (-2f, nh, nl, 1, 1, 0...), B' row = (f_, 1, 1, nh2, nl2, 0...)
//   => A'.B' = full squared distance straight out of MFMA.
// rowglob/colglob: per-point mins as float bits (int), atomicMin-accumulated; counter after them.
static const size_t OFF_A   = 0;
static const size_t OFF_B   = (size_t)B_ * N_ * KP * 2;                   // 6,291,456
static const size_t OFF_RG  = OFF_B + (size_t)B_ * M_ * KP * 2;           // 12,582,912
static const size_t OFF_CG  = OFF_RG + (size_t)B_ * N_ * 4;               // +128 KB
static const size_t OFF_CNT = OFF_CG + (size_t)B_ * M_ * 4;               // +128 KB

__device__ __forceinline__ short bf16bits(float x) {
    union { __hip_bfloat16 h; unsigned short u; } cv;
    cv.h = __float2bfloat16(x);
    return (short)cv.u;
}
__device__ __forceinline__ float min3f(float a, float b, float c) {
    return fminf(fminf(a, b), c);   // -> v_min3_f32
}

// ---------------- prep: K=96 fused-norm fragment layout; init min buffers + counter + out ----------------
__global__ __launch_bounds__(256) void chamfer_prep(
        const float* __restrict__ f, const float* __restrict__ f2,
        unsigned short* __restrict__ Ap, unsigned short* __restrict__ Bp,
        int* __restrict__ minbuf, float* __restrict__ out) {
    const int tid = threadIdx.x;
    const int gid = blockIdx.x * 256 + tid;
    if (gid == 0) out[0] = 0.f;
    if (gid <= 65536) minbuf[gid] = (gid == 65536) ? 0 : INF_BITS;  // rowglob+colglob+counter

    const int w = gid >> 6;                          // 16-row block id, 0..4095
    const int lane = tid & 63;
    const int q = lane >> 4, c = lane & 15;
    const bool isA = w < RBN;
    const int rb = isA ? w : w - RBN;
    const float* src = isA ? f : f2;
    unsigned short* dst = isA ? Ap : Bp;
    const float scale = isA ? -2.0f : 1.0f;          // fold the -2 into A; exact in bf16

    const float* row = src + ((size_t)rb * 16 + c) * 64;
    f32x4 u0 = *(const f32x4*)(row + q * 8);
    f32x4 u1 = *(const f32x4*)(row + q * 8 + 4);
    f32x4 u2 = *(const f32x4*)(row + 32 + q * 8);
    f32x4 u3 = *(const f32x4*)(row + 32 + q * 8 + 4);

    float ss = 0.f;
    #pragma unroll
    for (int k = 0; k < 4; k++)
        ss += u0[k] * u0[k] + u1[k] * u1[k] + u2[k] * u2[k] + u3[k] * u3[k];
    ss += __shfl_xor(ss, 16, 64);
    ss += __shfl_xor(ss, 32, 64);                    // full ||row c||^2 in every lane

    bhalf8 o0, o1;
    #pragma unroll
    for (int k = 0; k < 4; k++) {
        o0[k]     = bf16bits(u0[k] * scale);
        o0[4 + k] = bf16bits(u1[k] * scale);
        o1[k]     = bf16bits(u2[k] * scale);
        o1[4 + k] = bf16bits(u3[k] * scale);
    }
    bhalf8 o2 = {0, 0, 0, 0, 0, 0, 0, 0};            // k=64..95 zeros except q==0 lanes
    if (q == 0) {
        float nh = __bfloat162float(__float2bfloat16(ss));  // hi part, exact in bf16
        float nl = ss - nh;                                  // residual
        const short one = 0x3F80;                            // bf16 1.0
        if (isA) { o2[0] = bf16bits(nh); o2[1] = bf16bits(nl); o2[2] = one; o2[3] = one; }
        else     { o2[0] = one; o2[1] = one; o2[2] = bf16bits(nh); o2[3] = bf16bits(nl); }
    }
    *(bhalf8*)(dst + ((size_t)(rb * 3 + 0) * 64 + lane) * 8) = o0;
    *(bhalf8*)(dst + ((size_t)(rb * 3 + 1) * 64 + lane) * 8) = o1;
    *(bhalf8*)(dst + ((size_t)(rb * 3 + 2) * 64 + lane) * 8) = o2;
}

// ---------------- tile kernel: wait-free loop, plain ds_write col partials, fused finalize ----------------
// grid (mc=8, nt=64, b=4); wave tile 64 rows x 32 cols/step, 16 steps. Row-min in registers;
// col partial per owner (wr*4+q) via plain ds_write (stride 136 words -> uniform 2-way banks =
// free; each slot written exactly once -> no init, no atomics). Block end: LDS owner-reduce ->
// global atomicMin; last block (device counter) computes the scalar in-kernel.
// NOTE R8 post-mortem: __launch_bounds__(256,4) clamped arch regs to 128 -> ~60 regs spilled to
// scratch (70 MB scratch writes, tile 223us). Plain (256) lets the allocator pick ~96+AGPR.
__global__ __launch_bounds__(256) void chamfer_tile(
        const unsigned short* __restrict__ Ap, const unsigned short* __restrict__ Bp,
        int* __restrict__ rowglob, int* __restrict__ colglob,
        int* __restrict__ counter, float* __restrict__ out) {
    const int mc = blockIdx.x;   // 0..7 : 8-tile mt chunk
    const int nt = blockIdx.y;   // 0..63
    const int b  = blockIdx.z;   // 0..3
    const int tid = threadIdx.x;
    const int wave = tid >> 6, lane = tid & 63;
    const int wr = wave >> 1, wc = wave & 1;
    const int q = lane >> 4, c = lane & 15;

    __shared__ float colmin[8 * 8 * 136];   // [mtl][owner wr*4+q][136]; 34,816 B
    __shared__ int rowmin[128];
    if (tid < 128) rowmin[tid] = INF_BITS;
    __syncthreads();

    // A fragments: rows nt*128 + wr*64 + i*16 + c, 3 k-steps. Loaded once.
    const int rbA0 = b * 512 + nt * 8 + wr * 4;
    bhalf8 af[4][3];
    #pragma unroll
    for (int i = 0; i < 4; i++)
        #pragma unroll
        for (int ks = 0; ks < 3; ks++)
            af[i][ks] = *(const bhalf8*)(Ap + ((size_t)((rbA0 + i) * 3 + ks) * 64 + lane) * 8);

    f32x4 rv[4];                 // running row-min, rows i*16+q*4+r (this wave's 64 rows)
    #pragma unroll
    for (int i = 0; i < 4; i++) rv[i] = (f32x4){3.0e38f, 3.0e38f, 3.0e38f, 3.0e38f};

    const f32x4 zero4 = {0.f, 0.f, 0.f, 0.f};

    // LDS write base for this thread's owner slot (mtl/half/jj offsets are immediates)
    float* cbase = &colmin[(size_t)(wr * 4 + q) * 136 + wc * 64 + c];

    // step: rbB = b*512 + (mc*8+mtl)*8 + wc*4 + half*2 + jj; ptr stride 1536 shorts/rb
    const unsigned short* pE = Bp + (size_t)(b * 512 + mc * 64 + wc * 4) * 1536 + lane * 8;
    const unsigned short* pO = pE + 3072;   // half=1 -> +2 rb

    auto loadB = [&](const unsigned short* p, bhalf8 (&bf)[2][3]) {
        #pragma unroll
        for (int jj = 0; jj < 2; jj++)
            #pragma unroll
            for (int ks = 0; ks < 3; ks++)
                bf[jj][ks] = *(const bhalf8*)(p + jj * 1536 + ks * 512);
    };

    auto process = [&](int mtl, int half, bhalf8 (&bf)[2][3]) {
        f32x4 acc[4][2];
        #pragma unroll
        for (int i = 0; i < 4; i++)
            #pragma unroll
            for (int jj = 0; jj < 2; jj++)
                acc[i][jj] = __builtin_amdgcn_mfma_f32_16x16x32_bf16(af[i][0], bf[jj][0], zero4, 0, 0, 0);
        #pragma unroll
        for (int ks = 1; ks < 3; ks++)
            #pragma unroll
            for (int i = 0; i < 4; i++)
                #pragma unroll
                for (int jj = 0; jj < 2; jj++)
                    acc[i][jj] = __builtin_amdgcn_mfma_f32_16x16x32_bf16(af[i][ks], bf[jj][ks], acc[i][jj], 0, 0, 0);

        // row-min: 16 v_min3
        #pragma unroll
        for (int i = 0; i < 4; i++)
            #pragma unroll
            for (int r = 0; r < 4; r++)
                rv[i][r] = fminf(fminf(acc[i][0][r], acc[i][1][r]), rv[i][r]);

        // col partial over this lane's 16 rows: balanced min3 tree -> ONE plain ds_write
        #pragma unroll
        for (int jj = 0; jj < 2; jj++) {
            float t0 = min3f(acc[0][jj][0], acc[0][jj][1], acc[0][jj][2]);
            float t1 = min3f(acc[0][jj][3], acc[1][jj][0], acc[1][jj][1]);
            float t2 = min3f(acc[1][jj][2], acc[1][jj][3], acc[2][jj][0]);
            float t3 = min3f(acc[2][jj][1], acc[2][jj][2], acc[2][jj][3]);
            float t4 = min3f(acc[3][jj][0], acc[3][jj][1], acc[3][jj][2]);
            cbase[mtl * (8 * 136) + half * 32 + jj * 16]
                = fminf(min3f(t0, t1, t2), min3f(t3, t4, acc[3][jj][3]));
        }
    };

    bhalf8 bf0[2][3], bf1[2][3];
    loadB(pE, bf0);
    #pragma unroll 1
    for (int mtl = 0; mtl < 8; mtl++) {
        loadB(pO, bf1);
        process(mtl, 0, bf0);
        pE += 12288;
        if (mtl < 7) loadB(pE, bf0);
        process(mtl, 1, bf1);
        pO += 12288;
    }

    // row flush (once per block): LDS atomic combine across the 32 (wc,c) owners
    #pragma unroll
    for (int i = 0; i < 4; i++)
        #pragma unroll
        for (int r = 0; r < 4; r++)
            atomicMin(&rowmin[wr * 64 + i * 16 + q * 4 + r], __float_as_int(rv[i][r]));
    __syncthreads();   // drains all ds_writes + row atomics

    if (tid < 128)
        atomicMin(&rowglob[(size_t)(b * 64 + nt) * 128 + tid], rowmin[tid]);
    #pragma unroll
    for (int k = 0; k < 4; k++) {
        const int idx = k * 256 + tid;       // 0..1023 = mtl*128 + col
        const int mtl = idx >> 7, col = idx & 127;
        const float* cp = &colmin[(size_t)mtl * (8 * 136) + col];
        float m = min3f(cp[0], cp[136], cp[2 * 136]);
        m = fminf(m, min3f(cp[3 * 136], cp[4 * 136], cp[5 * 136]));
        m = fminf(m, fminf(cp[6 * 136], cp[7 * 136]));
        atomicMin(&colglob[(size_t)(b * 64 + mc * 8 + mtl) * 128 + col], __float_as_int(m));
    }

    // ---- last-block finalize (saves one kernel launch ~16us) ----
    __shared__ int amLast;
    __syncthreads();   // all global atomics of this block issued & drained (barrier waits vmcnt)
    if (tid == 0) {
        __threadfence();                                  // release our atomics
        amLast = (atomicAdd(counter, 1) == GRID_TILE - 1);
    }
    __syncthreads();
    if (amLast) {
        __threadfence();                                  // acquire others' atomics
        float s = 0.f;
        for (int i = tid; i < B_ * N_; i += 256) {
            int rb_ = __hip_atomic_load(&rowglob[i], __ATOMIC_RELAXED, __HIP_MEMORY_SCOPE_AGENT);
            int cb_ = __hip_atomic_load(&colglob[i], __ATOMIC_RELAXED, __HIP_MEMORY_SCOPE_AGENT);
            s += __int_as_float(rb_) + __int_as_float(cb_);
        }
        s *= (1.0f / ((float)B_ * (float)N_));            // N_ == M_
        __shared__ float sb[256];
        sb[tid] = s;
        __syncthreads();
        for (int st = 128; st > 0; st >>= 1) {
            if (tid < st) sb[tid] += sb[tid + st];
            __syncthreads();
        }
        if (tid == 0) out[0] = sb[0];
    }
}

extern "C" void kernel_launch(void* const* d_in, const int* in_sizes, int n_in,
                              void* d_out, int out_size, void* d_ws, size_t ws_size,
                              hipStream_t stream) {
    const float* f  = (const float*)d_in[0];
    const float* f2 = (const float*)d_in[1];
    char* ws = (char*)d_ws;
    unsigned short* Ap = (unsigned short*)(ws + OFF_A);
    unsigned short* Bp = (unsigned short*)(ws + OFF_B);
    int* rowglob = (int*)(ws + OFF_RG);
    int* colglob = (int*)(ws + OFF_CG);
    int* counter = (int*)(ws + OFF_CNT);
    float* out   = (float*)d_out;

    // prep: fragment layout + norm fusion; inits rowglob/colglob/counter/out
    chamfer_prep<<<dim3(1024), dim3(256), 0, stream>>>(f, f2, Ap, Bp, rowglob, out);

    // main: 2048 blocks; last block computes the scalar
    chamfer_tile<<<dim3(8, NT_, B_), dim3(256), 0, stream>>>(Ap, Bp, rowglob, colglob, counter, out);
}

// Round 11
// 183.610 us; speedup vs baseline: 1.5333x; 1.0004x over previous
//
#include <hip/hip_runtime.h>
#include <hip/hip_bf16.h>
#include <stdint.h>

// Problem constants (fixed by reference)
#define B_  4
#define N_  8192
#define M_  8192
#define D_  64
#define KP  96    // padded K: 64 data + (norm_hi, norm_lo, 1, 1) + 28 zeros
#define NT_ 64
#define MT_ 64
#define RBN ((B_ * N_) / 16)     // 2048 16-row blocks on A side
#define INF_BITS 0x7F800000      // +inf bits; signed-int min == float min for our range
#define GRID_TILE (8 * 64 * 4)   // tile grid size (mc,nt,b)

typedef __attribute__((ext_vector_type(8))) short bhalf8;   // 8 bf16 (MFMA A/B frag)
typedef __attribute__((ext_vector_type(4))) float f32x4;    // MFMA C/D frag

// ---- workspace layout (bytes) ----
// A'/B': bf16 fragment-chunk order: chunk(rb, ks, lane=q*16+c) = row (rb*16+c), k=ks*32+q*8..+7,
//        at ((rb*3+ks)*64+lane)*8 elems -> lane-contiguous 1KB fragment loads.
// K extension fuses norms: A' row = (-2f, nh, nl, 1, 1, 0...), B' row = (f_, 1, 1, nh2, nl2, 0...)
//   => A'.B' = full squared distance straight out of MFMA.
// rowglob/colglob: per-point mins as float bits (int), atomicMin-accumulated; counter after.
// LESSON (R5/R7/R9): tile kernel is TLP-limited on B-frag L2 latency; resident blocks/CU is set
// by LDS+regs. Keep LDS tiny (4.6 KB) and don't clamp regs (R8: launch_bounds min-waves -> spill).
static const size_t OFF_A   = 0;
static const size_t OFF_B   = (size_t)B_ * N_ * KP * 2;                   // 6,291,456
static const size_t OFF_RG  = OFF_B + (size_t)B_ * M_ * KP * 2;           // 12,582,912
static const size_t OFF_CG  = OFF_RG + (size_t)B_ * N_ * 4;               // +128 KB
static const size_t OFF_CNT = OFF_CG + (size_t)B_ * M_ * 4;               // +128 KB

__device__ __forceinline__ short bf16bits(float x) {
    union { __hip_bfloat16 h; unsigned short u; } cv;
    cv.h = __float2bfloat16(x);
    return (short)cv.u;
}
__device__ __forceinline__ float min3f(float a, float b, float c) {
    return fminf(fminf(a, b), c);   // -> v_min3_f32
}

// ---------------- prep: K=96 fused-norm fragment layout; init min buffers + counter + out ----------------
__global__ __launch_bounds__(256) void chamfer_prep(
        const float* __restrict__ f, const float* __restrict__ f2,
        unsigned short* __restrict__ Ap, unsigned short* __restrict__ Bp,
        int* __restrict__ minbuf, float* __restrict__ out) {
    const int tid = threadIdx.x;
    const int gid = blockIdx.x * 256 + tid;
    if (gid == 0) out[0] = 0.f;
    if (gid <= 65536) minbuf[gid] = (gid == 65536) ? 0 : INF_BITS;  // rowglob+colglob+counter

    const int w = gid >> 6;                          // 16-row block id, 0..4095
    const int lane = tid & 63;
    const int q = lane >> 4, c = lane & 15;
    const bool isA = w < RBN;
    const int rb = isA ? w : w - RBN;
    const float* src = isA ? f : f2;
    unsigned short* dst = isA ? Ap : Bp;
    const float scale = isA ? -2.0f : 1.0f;          // fold the -2 into A; exact in bf16

    const float* row = src + ((size_t)rb * 16 + c) * 64;
    f32x4 u0 = *(const f32x4*)(row + q * 8);
    f32x4 u1 = *(const f32x4*)(row + q * 8 + 4);
    f32x4 u2 = *(const f32x4*)(row + 32 + q * 8);
    f32x4 u3 = *(const f32x4*)(row + 32 + q * 8 + 4);

    float ss = 0.f;
    #pragma unroll
    for (int k = 0; k < 4; k++)
        ss += u0[k] * u0[k] + u1[k] * u1[k] + u2[k] * u2[k] + u3[k] * u3[k];
    ss += __shfl_xor(ss, 16, 64);
    ss += __shfl_xor(ss, 32, 64);                    // full ||row c||^2 in every lane

    bhalf8 o0, o1;
    #pragma unroll
    for (int k = 0; k < 4; k++) {
        o0[k]     = bf16bits(u0[k] * scale);
        o0[4 + k] = bf16bits(u1[k] * scale);
        o1[k]     = bf16bits(u2[k] * scale);
        o1[4 + k] = bf16bits(u3[k] * scale);
    }
    bhalf8 o2 = {0, 0, 0, 0, 0, 0, 0, 0};            // k=64..95 zeros except q==0 lanes
    if (q == 0) {
        float nh = __bfloat162float(__float2bfloat16(ss));  // hi part, exact in bf16
        float nl = ss - nh;                                  // residual
        const short one = 0x3F80;                            // bf16 1.0
        if (isA) { o2[0] = bf16bits(nh); o2[1] = bf16bits(nl); o2[2] = one; o2[3] = one; }
        else     { o2[0] = one; o2[1] = one; o2[2] = bf16bits(nh); o2[3] = bf16bits(nl); }
    }
    *(bhalf8*)(dst + ((size_t)(rb * 3 + 0) * 64 + lane) * 8) = o0;
    *(bhalf8*)(dst + ((size_t)(rb * 3 + 1) * 64 + lane) * 8) = o1;
    *(bhalf8*)(dst + ((size_t)(rb * 3 + 2) * 64 + lane) * 8) = o2;
}

// ---------------- tile kernel: R5 loop (4.6 KB LDS, ds_min) + global atomicMin + fused finalize ----------------
// grid (mc=8, nt=64, b=4) = 2048 blocks; wave tile 64 rows x 32 cols/step, 16 steps.
// Row-min in registers; col-min via fire-and-forget LDS atomicMin (tiny LDS keeps 8 blocks/CU
// resident -> latency hiding; R9's 35 KB LDS halved residency and doubled dur).
__global__ __launch_bounds__(256) void chamfer_tile(
        const unsigned short* __restrict__ Ap, const unsigned short* __restrict__ Bp,
        int* __restrict__ rowglob, int* __restrict__ colglob,
        int* __restrict__ counter, float* __restrict__ out) {
    const int mc = blockIdx.x;   // 0..7 : 8-tile mt chunk
    const int nt = blockIdx.y;   // 0..63
    const int b  = blockIdx.z;   // 0..3
    const int tid = threadIdx.x;
    const int wave = tid >> 6, lane = tid & 63;
    const int wr = wave >> 1, wc = wave & 1;
    const int q = lane >> 4, c = lane & 15;

    __shared__ int colmin[8][128];   // per-mt col mins, float bits, signed-int order (4 KB)
    __shared__ int rowmin[128];
    #pragma unroll
    for (int k = 0; k < 4; k++) ((int*)colmin)[k * 256 + tid] = INF_BITS;
    if (tid < 128) rowmin[tid] = INF_BITS;
    __syncthreads();

    // A fragments: rows nt*128 + wr*64 + i*16 + c, 3 k-steps. Loaded once.
    const int rbA0 = b * 512 + nt * 8 + wr * 4;
    bhalf8 af[4][3];
    #pragma unroll
    for (int i = 0; i < 4; i++)
        #pragma unroll
        for (int ks = 0; ks < 3; ks++)
            af[i][ks] = *(const bhalf8*)(Ap + ((size_t)((rbA0 + i) * 3 + ks) * 64 + lane) * 8);

    f32x4 rv[4];                 // running row-min, rows i*16+q*4+r (this wave's 64 rows)
    #pragma unroll
    for (int i = 0; i < 4; i++) rv[i] = (f32x4){3.0e38f, 3.0e38f, 3.0e38f, 3.0e38f};

    const f32x4 zero4 = {0.f, 0.f, 0.f, 0.f};

    // step: rbB = b*512 + (mc*8+mtl)*8 + wc*4 + half*2 + jj; ptr stride 1536 shorts/rb
    const unsigned short* pE = Bp + (size_t)(b * 512 + mc * 64 + wc * 4) * 1536 + lane * 8;
    const unsigned short* pO = pE + 3072;   // half=1 -> +2 rb

    auto loadB = [&](const unsigned short* p, bhalf8 (&bf)[2][3]) {
        #pragma unroll
        for (int jj = 0; jj < 2; jj++)
            #pragma unroll
            for (int ks = 0; ks < 3; ks++)
                bf[jj][ks] = *(const bhalf8*)(p + jj * 1536 + ks * 512);
    };

    auto process = [&](int mtl, int half, bhalf8 (&bf)[2][3]) {
        f32x4 acc[4][2];
        #pragma unroll
        for (int i = 0; i < 4; i++)
            #pragma unroll
            for (int jj = 0; jj < 2; jj++)
                acc[i][jj] = __builtin_amdgcn_mfma_f32_16x16x32_bf16(af[i][0], bf[jj][0], zero4, 0, 0, 0);
        #pragma unroll
        for (int ks = 1; ks < 3; ks++)
            #pragma unroll
            for (int i = 0; i < 4; i++)
                #pragma unroll
                for (int jj = 0; jj < 2; jj++)
                    acc[i][jj] = __builtin_amdgcn_mfma_f32_16x16x32_bf16(af[i][ks], bf[jj][ks], acc[i][jj], 0, 0, 0);
        // acc[i][jj][r] = d(row nt*128+wr*64+i*16+q*4+r, col (mc*8+mtl)*128+wc*64+half*32+jj*16+c)

        // row-min: 16 v_min3
        #pragma unroll
        for (int i = 0; i < 4; i++)
            #pragma unroll
            for (int r = 0; r < 4; r++)
                rv[i][r] = fminf(fminf(acc[i][0][r], acc[i][1][r]), rv[i][r]);

        // col-min over this lane's 16 rows: balanced min3 tree -> 1 fire-and-forget ds_min per jj
        #pragma unroll
        for (int jj = 0; jj < 2; jj++) {
            float t0 = min3f(acc[0][jj][0], acc[0][jj][1], acc[0][jj][2]);
            float t1 = min3f(acc[0][jj][3], acc[1][jj][0], acc[1][jj][1]);
            float t2 = min3f(acc[1][jj][2], acc[1][jj][3], acc[2][jj][0]);
            float t3 = min3f(acc[2][jj][1], acc[2][jj][2], acc[2][jj][3]);
            float t4 = min3f(acc[3][jj][0], acc[3][jj][1], acc[3][jj][2]);
            float t  = fminf(min3f(t0, t1, t2), min3f(t3, t4, acc[3][jj][3]));
            atomicMin(&colmin[mtl][wc * 64 + half * 32 + jj * 16 + c], __float_as_int(t));
        }
    };

    bhalf8 bf0[2][3], bf1[2][3];
    loadB(pE, bf0);
    #pragma unroll 1
    for (int mtl = 0; mtl < 8; mtl++) {
        loadB(pO, bf1);
        process(mtl, 0, bf0);
        pE += 12288;
        if (mtl < 7) loadB(pE, bf0);
        process(mtl, 1, bf1);
        pO += 12288;
    }

    // row flush: LDS atomic combine across the 32 (wc,c) owners, then global atomicMin
    #pragma unroll
    for (int i = 0; i < 4; i++)
        #pragma unroll
        for (int r = 0; r < 4; r++)
            atomicMin(&rowmin[wr * 64 + i * 16 + q * 4 + r], __float_as_int(rv[i][r]));
    __syncthreads();   // drains all LDS atomics

    if (tid < 128)
        atomicMin(&rowglob[(size_t)(b * 64 + nt) * 128 + tid], rowmin[tid]);
    #pragma unroll
    for (int k = 0; k < 4; k++) {
        const int idx = k * 256 + tid;       // 0..1023 = mtl*128 + col
        const int mtl = idx >> 7, col = idx & 127;
        atomicMin(&colglob[(size_t)(b * 64 + mc * 8 + mtl) * 128 + col], colmin[mtl][col]);
    }

    // ---- last-block finalize (saves one kernel launch ~15us) ----
    __shared__ int amLast;
    __syncthreads();
    if (tid == 0) {
        __threadfence();                                  // release our atomics
        amLast = (atomicAdd(counter, 1) == GRID_TILE - 1);
    }
    __syncthreads();
    if (amLast) {
        __threadfence();                                  // acquire others' atomics
        float s = 0.f;
        for (int i = tid; i < B_ * N_; i += 256) {
            int rb_ = __hip_atomic_load(&rowglob[i], __ATOMIC_RELAXED, __HIP_MEMORY_SCOPE_AGENT);
            int cb_ = __hip_atomic_load(&colglob[i], __ATOMIC_RELAXED, __HIP_MEMORY_SCOPE_AGENT);
            s += __int_as_float(rb_) + __int_as_float(cb_);
        }
        s *= (1.0f / ((float)B_ * (float)N_));            // N_ == M_
        __shared__ float sb[256];
        sb[tid] = s;
        __syncthreads();
        for (int st = 128; st > 0; st >>= 1) {
            if (tid < st) sb[tid] += sb[tid + st];
            __syncthreads();
        }
        if (tid == 0) out[0] = sb[0];
    }
}

extern "C" void kernel_launch(void* const* d_in, const int* in_sizes, int n_in,
                              void* d_out, int out_size, void* d_ws, size_t ws_size,
                              hipStream_t stream) {
    const float* f  = (const float*)d_in[0];
    const float* f2 = (const float*)d_in[1];
    char* ws = (char*)d_ws;
    unsigned short* Ap = (unsigned short*)(ws + OFF_A);
    unsigned short* Bp = (unsigned short*)(ws + OFF_B);
    int* rowglob = (int*)(ws + OFF_RG);
    int* colglob = (int*)(ws + OFF_CG);
    int* counter = (int*)(ws + OFF_CNT);
    float* out   = (float*)d_out;

    // prep: fragment layout + norm fusion; inits rowglob/colglob/counter/out
    chamfer_prep<<<dim3(1024), dim3(256), 0, stream>>>(f, f2, Ap, Bp, rowglob, out);

    // main: 2048 blocks; last block computes the scalar
    chamfer_tile<<<dim3(8, NT_, B_), dim3(256), 0, stream>>>(Ap, Bp, rowglob, colglob, counter, out);
}